// Round 1
// baseline (376.335 us; speedup 1.0000x reference)
//
#include <hip/hip_runtime.h>
#include <stdint.h>

#define NB 64      // batch
#define BT 512     // time steps
#define NH 768     // hidden
#define NL 9       // labels

// ---------------------------------------------------------------------------
// Kernel 1: logits = x @ W + b   (rows = B*T = 32768, K = 768, N = 9)
// wave-per-row; each lane preloads its W slice (12 h-values x 9 labels) into
// registers once; float4 x loads; butterfly reduce across 64 lanes.
// ---------------------------------------------------------------------------
__global__ __launch_bounds__(256) void gemm_kernel(
    const float* __restrict__ x, const float* __restrict__ W,
    const float* __restrict__ bias, float* __restrict__ logits)
{
    const int lane   = threadIdx.x & 63;
    const int wave   = (blockIdx.x * blockDim.x + threadIdx.x) >> 6;
    const int nwaves = (gridDim.x * blockDim.x) >> 6;

    // W slice for this lane position: h = k*256 + lane*4 + u
    float wr[3][4][NL];
#pragma unroll
    for (int k = 0; k < 3; ++k)
#pragma unroll
        for (int u = 0; u < 4; ++u) {
            const int h = k * 256 + lane * 4 + u;
#pragma unroll
            for (int l = 0; l < NL; ++l) wr[k][u][l] = W[h * NL + l];
        }
    const float bj = bias[lane < NL ? lane : 0];

    const int nrows = NB * BT;
    for (int row = wave; row < nrows; row += nwaves) {
        const float4* xr = (const float4*)(x + (size_t)row * NH);
        float acc[NL];
#pragma unroll
        for (int l = 0; l < NL; ++l) acc[l] = 0.f;
#pragma unroll
        for (int k = 0; k < 3; ++k) {
            const float4 xv = xr[k * 64 + lane];
#pragma unroll
            for (int l = 0; l < NL; ++l)
                acc[l] += xv.x * wr[k][0][l] + xv.y * wr[k][1][l] +
                          xv.z * wr[k][2][l] + xv.w * wr[k][3][l];
        }
        // butterfly reduce: all lanes end with full sums
#pragma unroll
        for (int off = 32; off >= 1; off >>= 1)
#pragma unroll
            for (int l = 0; l < NL; ++l) acc[l] += __shfl_xor(acc[l], off, 64);
        if (lane < NL) logits[(size_t)row * NL + lane] = acc[lane] + bj;
    }
}

// ---------------------------------------------------------------------------
// Kernel 2: per-batch CRF (one block per batch, 2 waves).
//   wave 0: forward scan (logZ lanes + viterbi lanes fused, bp -> LDS)
//   wave 1: gold-path score
//   then: pack bp rows into u64 (36 bits), fast backtrack, stats, vit output
// ---------------------------------------------------------------------------
__global__ __launch_bounds__(128) void crf_kernel(
    const float* __restrict__ logits, const float* __restrict__ trans,
    const int* __restrict__ label, const int* __restrict__ seqlen,
    float* __restrict__ vit_out, float* __restrict__ stats)
{
    __shared__ float    lg_lds[BT * NL];        // 18432 B
    __shared__ uint8_t  bp_lds[(BT - 1) * NL];  // 4599 B
    __shared__ uint64_t packed_lds[BT - 1];     // 4088 B
    __shared__ uint8_t  vit_lds[BT];            // 512 B
    __shared__ float    xw[4][2];

    const int b    = blockIdx.x;
    const int tid  = threadIdx.x;
    const int lane = tid & 63;
    const int wv   = tid >> 6;
    const int sl   = seqlen[b];
    const float* lg  = logits + (size_t)b * BT * NL;
    const int*   lab = label + (size_t)b * BT;

    // stage this batch's logits into LDS (coalesced)
    for (int idx = tid; idx < BT * NL; idx += 128) lg_lds[idx] = lg[idx];
    __syncthreads();

    if (wv == 0) {
        // ---- forward scan: lanes 0..8 own label columns ----
        const int j = lane < NL ? lane : 0;
        float tc[NL];
#pragma unroll
        for (int i = 0; i < NL; ++i) tc[i] = trans[i * NL + j];

        float a = lg_lds[j];   // logsumexp alpha (own column)
        float v = a;           // viterbi alpha
        // 2-deep logit prefetch from LDS
        float l1 = lg_lds[1 * NL + j];
        float l2 = lg_lds[2 * NL + j];
        for (int t = 1; t < BT; ++t) {
            const float l3 = (t + 2 < BT) ? lg_lds[(t + 2) * NL + j] : 0.f;
            float ai[NL], vi[NL];
#pragma unroll
            for (int i = 0; i < NL; ++i) {
                ai[i] = __shfl(a, i, 64);
                vi[i] = __shfl(v, i, 64);
            }
            // logsumexp update
            float sc[NL];
            sc[0] = ai[0] + tc[0];
            float m = sc[0];
#pragma unroll
            for (int i = 1; i < NL; ++i) { sc[i] = ai[i] + tc[i]; m = fmaxf(m, sc[i]); }
            float sum = 0.f;
#pragma unroll
            for (int i = 0; i < NL; ++i) sum += __expf(sc[i] - m);
            const float na = m + __logf(sum) + l1;
            // viterbi update (first-max tie semantics like np.argmax)
            float bv = vi[0] + tc[0]; int bi = 0;
#pragma unroll
            for (int i = 1; i < NL; ++i) {
                const float w = vi[i] + tc[i];
                if (w > bv) { bv = w; bi = i; }
            }
            const float nv = bv + l1;
            if (t < sl) { a = na; v = nv; } else { bi = j; }
            if (lane < NL) bp_lds[(t - 1) * NL + lane] = (uint8_t)bi;
            l1 = l2; l2 = l3;
        }
        // final logZ + last tag
        float ai[NL], vi[NL];
#pragma unroll
        for (int i = 0; i < NL; ++i) {
            ai[i] = __shfl(a, i, 64);
            vi[i] = __shfl(v, i, 64);
        }
        float m = ai[0];
#pragma unroll
        for (int i = 1; i < NL; ++i) m = fmaxf(m, ai[i]);
        float sum = 0.f;
#pragma unroll
        for (int i = 0; i < NL; ++i) sum += __expf(ai[i] - m);
        const float logZ = m + __logf(sum);
        float bv = vi[0]; int last = 0;
#pragma unroll
        for (int i = 1; i < NL; ++i)
            if (vi[i] > bv) { bv = vi[i]; last = i; }
        if (lane == 0) { stats[b * 8 + 1] = logZ; vit_lds[BT - 1] = (uint8_t)last; }
    } else {
        // ---- gold-path score ----
        float s = 0.f;
        for (int t = lane; t < BT; t += 64) {
            const int lb = lab[t];
            if (t < sl) {
                s += lg_lds[t * NL + lb];
                if (t >= 1) s += trans[lab[t - 1] * NL + lb];
            }
        }
#pragma unroll
        for (int off = 32; off >= 1; off >>= 1) s += __shfl_xor(s, off, 64);
        if (lane == 0) stats[b * 8 + 0] = s;
    }
    __syncthreads();

    // ---- pack bp rows: 9 x 4 bits -> u64 (all 128 threads) ----
    for (int r = tid; r < BT - 1; r += 128) {
        uint64_t p = 0;
#pragma unroll
        for (int i = 0; i < NL; ++i)
            p |= (uint64_t)bp_lds[r * NL + i] << (4 * i);
        packed_lds[r] = p;
    }
    __syncthreads();

    // ---- backtrack: prefetchable LDS row reads + VALU extract chain ----
    if (tid == 0) {
        int tag = vit_lds[BT - 1];
        for (int t = BT - 2; t >= 0; --t) {
            const uint64_t row = packed_lds[t];
            tag = (int)((row >> (4 * tag)) & 15u);
            vit_lds[t] = (uint8_t)tag;
        }
    }
    __syncthreads();

    // ---- stats + vit output ----
    float accv = 0.f, tpv = 0.f, tnv = 0.f, fpv = 0.f;
    for (int t = tid; t < BT; t += 128) {
        const int tg = vit_lds[t];
        const int lb = lab[t];
        const bool msk = t < sl;
        vit_out[(size_t)b * BT + t] = (float)tg;
        if (msk && tg == lb) accv += 1.f;
        if (lb > 0 && tg == lb) tpv += 1.f;
        if (lb > 0 && tg != lb) tnv += 1.f;
        if (msk && lb == 0 && tg > 0) fpv += 1.f;
    }
#pragma unroll
    for (int off = 32; off >= 1; off >>= 1) {
        accv += __shfl_xor(accv, off, 64);
        tpv  += __shfl_xor(tpv,  off, 64);
        tnv  += __shfl_xor(tnv,  off, 64);
        fpv  += __shfl_xor(fpv,  off, 64);
    }
    if (lane == 0) { xw[0][wv] = accv; xw[1][wv] = tpv; xw[2][wv] = tnv; xw[3][wv] = fpv; }
    __syncthreads();
    if (tid == 0) {
        stats[b * 8 + 2] = xw[0][0] + xw[0][1];
        stats[b * 8 + 3] = xw[1][0] + xw[1][1];
        stats[b * 8 + 4] = xw[2][0] + xw[2][1];
        stats[b * 8 + 5] = xw[3][0] + xw[3][1];
    }
}

// ---------------------------------------------------------------------------
// Kernel 3: reduce the 64 per-batch partials -> tp, tn, fp, loss, accuracy
// ---------------------------------------------------------------------------
__global__ __launch_bounds__(64) void finalize_kernel(
    const float* __restrict__ stats, const int* __restrict__ seqlen,
    float* __restrict__ out)
{
    const int lane = threadIdx.x;  // one lane per batch
    float score = stats[lane * 8 + 0];
    float logZ  = stats[lane * 8 + 1];
    float accv  = stats[lane * 8 + 2];
    float tpv   = stats[lane * 8 + 3];
    float tnv   = stats[lane * 8 + 4];
    float fpv   = stats[lane * 8 + 5];
    float nll   = logZ - score;
    float slf   = (float)seqlen[lane];
#pragma unroll
    for (int off = 32; off >= 1; off >>= 1) {
        nll  += __shfl_xor(nll,  off, 64);
        accv += __shfl_xor(accv, off, 64);
        tpv  += __shfl_xor(tpv,  off, 64);
        tnv  += __shfl_xor(tnv,  off, 64);
        fpv  += __shfl_xor(fpv,  off, 64);
        slf  += __shfl_xor(slf,  off, 64);
    }
    if (lane == 0) {
        out[NB * BT + 0] = tpv;
        out[NB * BT + 1] = tnv;
        out[NB * BT + 2] = fpv;
        out[NB * BT + 3] = nll / (float)NB;
        out[NB * BT + 4] = accv / slf;
    }
}

extern "C" void kernel_launch(void* const* d_in, const int* in_sizes, int n_in,
                              void* d_out, int out_size, void* d_ws, size_t ws_size,
                              hipStream_t stream)
{
    const float* x      = (const float*)d_in[0];
    const float* W      = (const float*)d_in[1];
    const float* bias   = (const float*)d_in[2];
    const float* trans  = (const float*)d_in[3];
    const int*   label  = (const int*)d_in[4];
    const int*   seqlen = (const int*)d_in[5];
    // d_in[6] = mask: recomputed from seqlen, unused

    float* out    = (float*)d_out;
    float* logits = (float*)d_ws;                  // 64*512*9 floats
    float* stats  = logits + (size_t)NB * BT * NL; // 64*8 floats

    gemm_kernel<<<768, 256, 0, stream>>>(x, W, bias, logits);
    crf_kernel<<<NB, 128, 0, stream>>>(logits, trans, label, seqlen, out, stats);
    finalize_kernel<<<1, 64, 0, stream>>>(stats, seqlen, out);
}

// Round 2
// 262.939 us; speedup vs baseline: 1.4313x; 1.4313x over previous
//
#include <hip/hip_runtime.h>
#include <stdint.h>

#define NB 64      // batch
#define BT 512     // time steps
#define NH 768     // hidden
#define NL 9       // labels

__device__ __forceinline__ float rlane(float v, int i) {
    return __int_as_float(__builtin_amdgcn_readlane(__float_as_int(v), i));
}

// ---------------------------------------------------------------------------
// Kernel 1: logits = x @ W + b   (rows = B*T = 32768, K = 768, N = 9)
// wave-per-row; per-lane W register cache; float4 x loads; butterfly reduce.
// NOTE: epilogue uses a static-index cndmask chain (no dynamic acc[lane]
// indexing -> no scratch spill of the accumulator array).
// ---------------------------------------------------------------------------
__global__ __launch_bounds__(256, 1) void gemm_kernel(
    const float* __restrict__ x, const float* __restrict__ W,
    const float* __restrict__ bias, float* __restrict__ logits)
{
    const int lane   = threadIdx.x & 63;
    const int wave   = (blockIdx.x * blockDim.x + threadIdx.x) >> 6;
    const int nwaves = (gridDim.x * blockDim.x) >> 6;

    // W slice for this lane position: h = k*256 + lane*4 + u
    float wr[3][4][NL];
#pragma unroll
    for (int k = 0; k < 3; ++k)
#pragma unroll
        for (int u = 0; u < 4; ++u) {
            const int h = k * 256 + lane * 4 + u;
#pragma unroll
            for (int l = 0; l < NL; ++l) wr[k][u][l] = W[h * NL + l];
        }
    const float bj = bias[lane < NL ? lane : 0];

    const int nrows = NB * BT;
    for (int row = wave; row < nrows; row += nwaves) {
        const float4* xr = (const float4*)(x + (size_t)row * NH);
        float acc[NL];
#pragma unroll
        for (int l = 0; l < NL; ++l) acc[l] = 0.f;
#pragma unroll
        for (int k = 0; k < 3; ++k) {
            const float4 xv = xr[k * 64 + lane];
#pragma unroll
            for (int l = 0; l < NL; ++l)
                acc[l] += xv.x * wr[k][0][l] + xv.y * wr[k][1][l] +
                          xv.z * wr[k][2][l] + xv.w * wr[k][3][l];
        }
        // butterfly reduce: all lanes end with full sums
#pragma unroll
        for (int off = 32; off >= 1; off >>= 1)
#pragma unroll
            for (int l = 0; l < NL; ++l) acc[l] += __shfl_xor(acc[l], off, 64);
        // static-index select: outv = acc[lane] without dynamic indexing
        float outv = acc[0];
#pragma unroll
        for (int l = 1; l < NL; ++l) outv = (lane == l) ? acc[l] : outv;
        if (lane < NL) logits[(size_t)row * NL + lane] = outv + bj;
    }
}

// ---------------------------------------------------------------------------
// Kernel 2: per-batch CRF (one block per batch, 4 waves).
//   wave 0: logZ forward scan (exp-trick: one exp per lane per step)
//   wave 1: viterbi forward scan (tournament argmax), bp -> LDS
//   wave 2: gold-path score
//   then: pack bp rows to u64 nibbles, fast backtrack, stats, vit output
// ---------------------------------------------------------------------------
__global__ __launch_bounds__(256) void crf_kernel(
    const float* __restrict__ logits, const float* __restrict__ trans,
    const int* __restrict__ label, const int* __restrict__ seqlen,
    float* __restrict__ vit_out, float* __restrict__ stats)
{
    __shared__ __align__(16) float lg_lds[BT * NL];  // 18432 B
    __shared__ uint8_t  bp_lds[(BT - 1) * NL];       // 4599 B
    __shared__ uint64_t packed_lds[BT - 1];          // 4088 B
    __shared__ uint8_t  vit_lds[BT];                 // 512 B
    __shared__ float    xw[4][4];

    const int b    = blockIdx.x;
    const int tid  = threadIdx.x;
    const int lane = tid & 63;
    const int wv   = tid >> 6;
    const int sl   = seqlen[b];
    const float* lg  = logits + (size_t)b * BT * NL;
    const int*   lab = label + (size_t)b * BT;

    // stage this batch's logits into LDS (coalesced float4)
    {
        const float4* src = (const float4*)lg;
        float4* dst = (float4*)lg_lds;
        for (int idx = tid; idx < BT * NL / 4; idx += 256) dst[idx] = src[idx];
    }
    __syncthreads();

    if (wv == 0) {
        // ---- logZ scan: lane j owns column j; exp(T) precomputed ----
        const int j = lane < NL ? lane : 0;
        float E[NL];
#pragma unroll
        for (int i = 0; i < NL; ++i) E[i] = __expf(trans[i * NL + j]);

        float a  = lg_lds[j];
        float l1 = lg_lds[1 * NL + j];
        float l2 = lg_lds[2 * NL + j];
        for (int t = 1; t < BT; ++t) {
            const float l3 = (t + 2 < BT) ? lg_lds[(t + 2) * NL + j] : 0.f;
            // broadcast alpha, global max (tree)
            const float r0 = rlane(a, 0), r1 = rlane(a, 1), r2 = rlane(a, 2),
                        r3 = rlane(a, 3), r4 = rlane(a, 4), r5 = rlane(a, 5),
                        r6 = rlane(a, 6), r7 = rlane(a, 7), r8 = rlane(a, 8);
            const float m01 = fmaxf(r0, r1), m23 = fmaxf(r2, r3);
            const float m45 = fmaxf(r4, r5), m67 = fmaxf(r6, r7);
            const float m03 = fmaxf(m01, m23), m47 = fmaxf(m45, m67);
            const float m   = fmaxf(fmaxf(m03, m47), r8);
            // one exp per lane, then broadcast e
            const float e = __expf(a - m);
            const float e0 = rlane(e, 0), e1 = rlane(e, 1), e2 = rlane(e, 2),
                        e3 = rlane(e, 3), e4 = rlane(e, 4), e5 = rlane(e, 5),
                        e6 = rlane(e, 6), e7 = rlane(e, 7), e8 = rlane(e, 8);
            float s0 = e0 * E[0];
            float s1 = e1 * E[1];
            s0 = fmaf(e2, E[2], s0); s1 = fmaf(e3, E[3], s1);
            s0 = fmaf(e4, E[4], s0); s1 = fmaf(e5, E[5], s1);
            s0 = fmaf(e6, E[6], s0); s1 = fmaf(e7, E[7], s1);
            s0 = fmaf(e8, E[8], s0);
            const float na = m + __logf(s0 + s1) + l1;
            if (t < sl) a = na;
            l1 = l2; l2 = l3;
        }
        // final logZ = logsumexp(alphaT)
        const float r0 = rlane(a, 0), r1 = rlane(a, 1), r2 = rlane(a, 2),
                    r3 = rlane(a, 3), r4 = rlane(a, 4), r5 = rlane(a, 5),
                    r6 = rlane(a, 6), r7 = rlane(a, 7), r8 = rlane(a, 8);
        const float m01 = fmaxf(r0, r1), m23 = fmaxf(r2, r3);
        const float m45 = fmaxf(r4, r5), m67 = fmaxf(r6, r7);
        const float m = fmaxf(fmaxf(fmaxf(m01, m23), fmaxf(m45, m67)), r8);
        float sum = __expf(r0 - m) + __expf(r1 - m) + __expf(r2 - m) +
                    __expf(r3 - m) + __expf(r4 - m) + __expf(r5 - m) +
                    __expf(r6 - m) + __expf(r7 - m) + __expf(r8 - m);
        if (lane == 0) stats[b * 8 + 1] = m + __logf(sum);
    } else if (wv == 1) {
        // ---- viterbi scan: tournament argmax (first-max semantics) ----
        const int j = lane < NL ? lane : 0;
        float tc[NL];
#pragma unroll
        for (int i = 0; i < NL; ++i) tc[i] = trans[i * NL + j];

        float v  = lg_lds[j];
        float l1 = lg_lds[1 * NL + j];
        float l2 = lg_lds[2 * NL + j];
        for (int t = 1; t < BT; ++t) {
            const float l3 = (t + 2 < BT) ? lg_lds[(t + 2) * NL + j] : 0.f;
            const float r0 = rlane(v, 0), r1 = rlane(v, 1), r2 = rlane(v, 2),
                        r3 = rlane(v, 3), r4 = rlane(v, 4), r5 = rlane(v, 5),
                        r6 = rlane(v, 6), r7 = rlane(v, 7), r8 = rlane(v, 8);
            const float c0 = r0 + tc[0], c1 = r1 + tc[1], c2 = r2 + tc[2],
                        c3 = r3 + tc[3], c4 = r4 + tc[4], c5 = r5 + tc[5],
                        c6 = r6 + tc[6], c7 = r7 + tc[7], c8 = r8 + tc[8];
            // tournament, right wins only on strict > (preserves first-max)
            float v01 = (c1 > c0) ? c1 : c0; int i01 = (c1 > c0) ? 1 : 0;
            float v23 = (c3 > c2) ? c3 : c2; int i23 = (c3 > c2) ? 3 : 2;
            float v45 = (c5 > c4) ? c5 : c4; int i45 = (c5 > c4) ? 5 : 4;
            float v67 = (c7 > c6) ? c7 : c6; int i67 = (c7 > c6) ? 7 : 6;
            float v03 = (v23 > v01) ? v23 : v01; int i03 = (v23 > v01) ? i23 : i01;
            float v47 = (v67 > v45) ? v67 : v45; int i47 = (v67 > v45) ? i67 : i45;
            float v07 = (v47 > v03) ? v47 : v03; int i07 = (v47 > v03) ? i47 : i03;
            float bv  = (c8 > v07) ? c8 : v07;  int bi  = (c8 > v07) ? 8 : i07;
            const float nv = bv + l1;
            int outb;
            if (t < sl) { v = nv; outb = bi; } else outb = j;
            if (lane < NL) bp_lds[(t - 1) * NL + lane] = (uint8_t)outb;
            l1 = l2; l2 = l3;
        }
        // last = argmax(alphaT) (first-max)
        const float r0 = rlane(v, 0), r1 = rlane(v, 1), r2 = rlane(v, 2),
                    r3 = rlane(v, 3), r4 = rlane(v, 4), r5 = rlane(v, 5),
                    r6 = rlane(v, 6), r7 = rlane(v, 7), r8 = rlane(v, 8);
        float v01 = (r1 > r0) ? r1 : r0; int i01 = (r1 > r0) ? 1 : 0;
        float v23 = (r3 > r2) ? r3 : r2; int i23 = (r3 > r2) ? 3 : 2;
        float v45 = (r5 > r4) ? r5 : r4; int i45 = (r5 > r4) ? 5 : 4;
        float v67 = (r7 > r6) ? r7 : r6; int i67 = (r7 > r6) ? 7 : 6;
        float v03 = (v23 > v01) ? v23 : v01; int i03 = (v23 > v01) ? i23 : i01;
        float v47 = (v67 > v45) ? v67 : v45; int i47 = (v67 > v45) ? i67 : i45;
        float v07 = (v47 > v03) ? v47 : v03; int i07 = (v47 > v03) ? i47 : i03;
        int last = (r8 > v07) ? 8 : i07;
        if (lane == 0) vit_lds[BT - 1] = (uint8_t)last;
    } else if (wv == 2) {
        // ---- gold-path score ----
        float s = 0.f;
        for (int t = lane; t < BT; t += 64) {
            const int lb = lab[t];
            if (t < sl) {
                s += lg_lds[t * NL + lb];
                if (t >= 1) s += trans[lab[t - 1] * NL + lb];
            }
        }
#pragma unroll
        for (int off = 32; off >= 1; off >>= 1) s += __shfl_xor(s, off, 64);
        if (lane == 0) stats[b * 8 + 0] = s;
    }
    __syncthreads();

    // ---- pack bp rows: 9 x 4 bits -> u64 ----
    for (int r = tid; r < BT - 1; r += 256) {
        uint64_t p = 0;
#pragma unroll
        for (int i = 0; i < NL; ++i)
            p |= (uint64_t)bp_lds[r * NL + i] << (4 * i);
        packed_lds[r] = p;
    }
    __syncthreads();

    // ---- backtrack: sequential LDS row reads (address-independent,
    //      prefetchable) + 2-op extract chain ----
    if (tid == 0) {
        int tag = vit_lds[BT - 1];
        for (int t = BT - 2; t >= 0; --t) {
            const uint64_t row = packed_lds[t];
            tag = (int)((row >> (4 * tag)) & 15u);
            vit_lds[t] = (uint8_t)tag;
        }
    }
    __syncthreads();

    // ---- stats + vit output ----
    float accv = 0.f, tpv = 0.f, tnv = 0.f, fpv = 0.f;
    for (int t = tid; t < BT; t += 256) {
        const int tg = vit_lds[t];
        const int lb = lab[t];
        const bool msk = t < sl;
        vit_out[(size_t)b * BT + t] = (float)tg;
        if (msk && tg == lb) accv += 1.f;
        if (lb > 0 && tg == lb) tpv += 1.f;
        if (lb > 0 && tg != lb) tnv += 1.f;
        if (msk && lb == 0 && tg > 0) fpv += 1.f;
    }
#pragma unroll
    for (int off = 32; off >= 1; off >>= 1) {
        accv += __shfl_xor(accv, off, 64);
        tpv  += __shfl_xor(tpv,  off, 64);
        tnv  += __shfl_xor(tnv,  off, 64);
        fpv  += __shfl_xor(fpv,  off, 64);
    }
    if (lane == 0) { xw[0][wv] = accv; xw[1][wv] = tpv; xw[2][wv] = tnv; xw[3][wv] = fpv; }
    __syncthreads();
    if (tid == 0) {
        stats[b * 8 + 2] = xw[0][0] + xw[0][1] + xw[0][2] + xw[0][3];
        stats[b * 8 + 3] = xw[1][0] + xw[1][1] + xw[1][2] + xw[1][3];
        stats[b * 8 + 4] = xw[2][0] + xw[2][1] + xw[2][2] + xw[2][3];
        stats[b * 8 + 5] = xw[3][0] + xw[3][1] + xw[3][2] + xw[3][3];
    }
}

// ---------------------------------------------------------------------------
// Kernel 3: reduce the 64 per-batch partials -> tp, tn, fp, loss, accuracy
// ---------------------------------------------------------------------------
__global__ __launch_bounds__(64) void finalize_kernel(
    const float* __restrict__ stats, const int* __restrict__ seqlen,
    float* __restrict__ out)
{
    const int lane = threadIdx.x;  // one lane per batch
    float score = stats[lane * 8 + 0];
    float logZ  = stats[lane * 8 + 1];
    float accv  = stats[lane * 8 + 2];
    float tpv   = stats[lane * 8 + 3];
    float tnv   = stats[lane * 8 + 4];
    float fpv   = stats[lane * 8 + 5];
    float nll   = logZ - score;
    float slf   = (float)seqlen[lane];
#pragma unroll
    for (int off = 32; off >= 1; off >>= 1) {
        nll  += __shfl_xor(nll,  off, 64);
        accv += __shfl_xor(accv, off, 64);
        tpv  += __shfl_xor(tpv,  off, 64);
        tnv  += __shfl_xor(tnv,  off, 64);
        fpv  += __shfl_xor(fpv,  off, 64);
        slf  += __shfl_xor(slf,  off, 64);
    }
    if (lane == 0) {
        out[NB * BT + 0] = tpv;
        out[NB * BT + 1] = tnv;
        out[NB * BT + 2] = fpv;
        out[NB * BT + 3] = nll / (float)NB;
        out[NB * BT + 4] = accv / slf;
    }
}

extern "C" void kernel_launch(void* const* d_in, const int* in_sizes, int n_in,
                              void* d_out, int out_size, void* d_ws, size_t ws_size,
                              hipStream_t stream)
{
    const float* x      = (const float*)d_in[0];
    const float* W      = (const float*)d_in[1];
    const float* bias   = (const float*)d_in[2];
    const float* trans  = (const float*)d_in[3];
    const int*   label  = (const int*)d_in[4];
    const int*   seqlen = (const int*)d_in[5];
    // d_in[6] = mask: recomputed from seqlen, unused

    float* out    = (float*)d_out;
    float* logits = (float*)d_ws;                  // 64*512*9 floats
    float* stats  = logits + (size_t)NB * BT * NL; // 64*8 floats

    gemm_kernel<<<768, 256, 0, stream>>>(x, W, bias, logits);
    crf_kernel<<<NB, 256, 0, stream>>>(logits, trans, label, seqlen, out, stats);
    finalize_kernel<<<1, 64, 0, stream>>>(stats, seqlen, out);
}

// Round 4
// 233.452 us; speedup vs baseline: 1.6120x; 1.1263x over previous
//
#include <hip/hip_runtime.h>
#include <stdint.h>
#include <math.h>

#define NB 64      // batch
#define BT 512     // time steps
#define NH 768     // hidden
#define NL 9       // labels
#define KQ 192     // K-range per wave in gemm (768/4)
#define PBT 528    // padded time rows in crf LDS

__device__ __forceinline__ float rlane(float v, int i) {
    return __int_as_float(__builtin_amdgcn_readlane(__float_as_int(v), i));
}

// ---------------------------------------------------------------------------
// Kernel 1: logits = x @ W + b.  Thread-per-row, K split across 4 waves.
// W index is wave-uniform -> scalar s_load broadcasts (no per-lane W traffic,
// no LDS reads in the hot loop). Cross-wave combine via one LDS round-trip.
// ---------------------------------------------------------------------------
__global__ __launch_bounds__(256) void gemm_kernel(
    const float* __restrict__ x, const float* __restrict__ W,
    const float* __restrict__ bias, float* __restrict__ logits)
{
    __shared__ float part[4][64][12];   // padded inner stride
    const int lane    = threadIdx.x & 63;
    const int wv      = threadIdx.x >> 6;     // K-quarter
    const int rowbase = blockIdx.x * 64;
    const float4* xr = (const float4*)(x + (size_t)(rowbase + lane) * NH + wv * KQ);
    const float*  wq = W + wv * KQ * NL;

    float acc[NL];
#pragma unroll
    for (int l = 0; l < NL; ++l) acc[l] = 0.f;

#pragma unroll 8
    for (int k4 = 0; k4 < KQ / 4; ++k4) {
        const float4 xv = xr[k4];
        const float* wp = wq + k4 * 4 * NL;   // uniform -> scalar loads
#pragma unroll
        for (int l = 0; l < NL; ++l)
            acc[l] = fmaf(xv.x, wp[l],
                     fmaf(xv.y, wp[NL + l],
                     fmaf(xv.z, wp[2 * NL + l],
                     fmaf(xv.w, wp[3 * NL + l], acc[l]))));
    }
#pragma unroll
    for (int l = 0; l < NL; ++l) part[wv][lane][l] = acc[l];
    __syncthreads();
    for (int o = threadIdx.x; o < 64 * NL; o += 256) {
        const int r = o / NL, l = o - r * NL;
        const float s = part[0][r][l] + part[1][r][l] + part[2][r][l] + part[3][r][l];
        logits[(size_t)(rowbase + r) * NL + l] = s + bias[l];
    }
}

// ---------------------------------------------------------------------------
// Kernel 2: per-batch CRF. Block = 256 (4 waves).
//   wave 0: logZ scan in scaled-exp domain (exp/log OUT of the recurrence;
//           exact pow2 renorm every 8 steps via bit-level frexp/ldexp)
//   wave 1: viterbi value-only scan (max3 tree), alpha vectors -> LDS
//   wave 2: gold-path score
//   post:   parallel backpointer recompute, nibble-pack, serial backtrack,
//           stats.
// ---------------------------------------------------------------------------
__global__ __launch_bounds__(256) void crf_kernel(
    const float* __restrict__ logits, const float* __restrict__ trans,
    const int* __restrict__ label, const int* __restrict__ seqlen,
    float* __restrict__ vit_out, float* __restrict__ stats)
{
    __shared__ __align__(16) float lg_lds[PBT * NL];   // 19008 B (padded, zeros past BT)
    __shared__ float    val_lds[BT * NL];              // viterbi alpha vectors
    __shared__ float    trans_lds[NL * NL];
    __shared__ uint8_t  bp_lds[(BT - 1) * NL];
    __shared__ uint64_t packed_lds[BT - 1];
    __shared__ uint8_t  vit_lds[BT];
    __shared__ float    xw[4][4];

    const int b    = blockIdx.x;
    const int tid  = threadIdx.x;
    const int lane = tid & 63;
    const int wv   = tid >> 6;
    const int sl   = seqlen[b];
    const float* lg  = logits + (size_t)b * BT * NL;
    const int*   lab = label + (size_t)b * BT;

    // stage logits (float4) + zero padding + transitions
    {
        const float4* src = (const float4*)lg;
        float4* dst = (float4*)lg_lds;
        for (int idx = tid; idx < BT * NL / 4; idx += 256) dst[idx] = src[idx];
        for (int idx = BT * NL + tid; idx < PBT * NL; idx += 256) lg_lds[idx] = 0.f;
        if (tid < NL * NL) trans_lds[tid] = trans[tid];
    }
    __syncthreads();

    if (wv == 0) {
        // ---- logZ scan, scaled-exp domain ----
        const int j = lane < NL ? lane : 0;
        float E[NL];
#pragma unroll
        for (int i = 0; i < NL; ++i) E[i] = __expf(trans_lds[i * NL + j]) * 0.125f;
        float A = __expf(lg_lds[j]);
        int lc = 0;
        for (int tb = 1; tb < BT + 8; tb += 8) {
            float P[8];
#pragma unroll
            for (int s = 0; s < 8; ++s) P[s] = __expf(lg_lds[(tb + s) * NL + j]);
#pragma unroll
            for (int s = 0; s < 8; ++s) {
                const int t = tb + s;
                const float r0 = rlane(A, 0), r1 = rlane(A, 1), r2 = rlane(A, 2),
                            r3 = rlane(A, 3), r4 = rlane(A, 4), r5 = rlane(A, 5),
                            r6 = rlane(A, 6), r7 = rlane(A, 7), r8 = rlane(A, 8);
                float p0 = r0 * E[0]; p0 = fmaf(r1, E[1], p0); p0 = fmaf(r2, E[2], p0);
                float p1 = r3 * E[3]; p1 = fmaf(r4, E[4], p1); p1 = fmaf(r5, E[5], p1);
                float p2 = r6 * E[6]; p2 = fmaf(r7, E[7], p2); p2 = fmaf(r8, E[8], p2);
                const float An = ((p0 + p1) + p2) * P[s];
                A = (t < sl) ? An : A;
            }
            // exact pow2 renorm: m is positive & normal here.
            const float m = fmaxf(fmaxf(
                fmaxf(fmaxf(rlane(A, 0), rlane(A, 1)), fmaxf(rlane(A, 2), rlane(A, 3))),
                fmaxf(fmaxf(rlane(A, 4), rlane(A, 5)), fmaxf(rlane(A, 6), rlane(A, 7)))),
                rlane(A, 8));
            const int ex = (int)((__float_as_uint(m) >> 23) & 0xFFu) - 126; // frexp exp
            const float sc = __uint_as_float((uint32_t)(127 - ex) << 23);   // 2^-ex
            A *= sc;
            lc += ex;
        }
        const float sum = ((rlane(A, 0) + rlane(A, 1)) + (rlane(A, 2) + rlane(A, 3))) +
                          ((rlane(A, 4) + rlane(A, 5)) + (rlane(A, 6) + rlane(A, 7))) +
                          rlane(A, 8);
        const float logZ = logf(sum) +
            ((float)lc + 3.0f * (float)(sl - 1)) * 0.6931471805599453f;
        if (lane == 0) stats[b * 8 + 1] = logZ;
    } else if (wv == 1) {
        // ---- viterbi value scan; alpha vectors to LDS, argmax deferred ----
        const int j = lane < NL ? lane : 0;
        float tc[NL];
#pragma unroll
        for (int i = 0; i < NL; ++i) tc[i] = trans_lds[i * NL + j];
        float v = lg_lds[j];
        if (lane < NL) val_lds[j] = v;
        for (int tb = 1; tb < BT + 8; tb += 8) {
            float lv[8];
#pragma unroll
            for (int s = 0; s < 8; ++s) lv[s] = lg_lds[(tb + s) * NL + j];
#pragma unroll
            for (int s = 0; s < 8; ++s) {
                const int t = tb + s;
                const float r0 = rlane(v, 0), r1 = rlane(v, 1), r2 = rlane(v, 2),
                            r3 = rlane(v, 3), r4 = rlane(v, 4), r5 = rlane(v, 5),
                            r6 = rlane(v, 6), r7 = rlane(v, 7), r8 = rlane(v, 8);
                const float c0 = r0 + tc[0], c1 = r1 + tc[1], c2 = r2 + tc[2],
                            c3 = r3 + tc[3], c4 = r4 + tc[4], c5 = r5 + tc[5],
                            c6 = r6 + tc[6], c7 = r7 + tc[7], c8 = r8 + tc[8];
                const float m = fmaxf(fmaxf(fmaxf(fmaxf(c0, c1), c2),
                                            fmaxf(fmaxf(c3, c4), c5)),
                                      fmaxf(fmaxf(c6, c7), c8));
                const float nv = m + lv[s];
                v = (t < sl) ? nv : v;
                if (lane < NL && t < BT) val_lds[t * NL + lane] = v;
            }
        }
        // last tag = first-argmax(alphaT)
        const float r0 = rlane(v, 0), r1 = rlane(v, 1), r2 = rlane(v, 2),
                    r3 = rlane(v, 3), r4 = rlane(v, 4), r5 = rlane(v, 5),
                    r6 = rlane(v, 6), r7 = rlane(v, 7), r8 = rlane(v, 8);
        const float m = fmaxf(fmaxf(fmaxf(fmaxf(r0, r1), r2),
                                    fmaxf(fmaxf(r3, r4), r5)),
                              fmaxf(fmaxf(r6, r7), r8));
        const int last = (r0 == m) ? 0 : (r1 == m) ? 1 : (r2 == m) ? 2 :
                         (r3 == m) ? 3 : (r4 == m) ? 4 : (r5 == m) ? 5 :
                         (r6 == m) ? 6 : (r7 == m) ? 7 : 8;
        if (lane == 0) vit_lds[BT - 1] = (uint8_t)last;
    } else if (wv == 2) {
        // ---- gold-path score ----
        float s = 0.f;
        for (int t = lane; t < BT; t += 64) {
            const int lb = lab[t];
            if (t < sl) {
                s += lg_lds[t * NL + lb];
                if (t >= 1) s += trans_lds[lab[t - 1] * NL + lb];
            }
        }
#pragma unroll
        for (int off = 32; off >= 1; off >>= 1) s += __shfl_xor(s, off, 64);
        if (lane == 0) stats[b * 8 + 0] = s;
    }
    __syncthreads();

    // ---- recompute backpointers in parallel (bit-exact first-max) ----
    for (int idx = tid; idx < (BT - 1) * NL; idx += 256) {
        const int tm1 = idx / NL;
        const int jj  = idx - tm1 * NL;
        const int t   = tm1 + 1;
        int bi;
        if (t >= sl) bi = jj;
        else {
            float best = val_lds[tm1 * NL] + trans_lds[jj];
            bi = 0;
#pragma unroll
            for (int i = 1; i < NL; ++i) {
                const float c = val_lds[tm1 * NL + i] + trans_lds[i * NL + jj];
                if (c > best) { best = c; bi = i; }
            }
        }
        bp_lds[idx] = (uint8_t)bi;
    }
    __syncthreads();

    // ---- pack bp rows: 9 x 4 bits -> u64 ----
    for (int r = tid; r < BT - 1; r += 256) {
        uint64_t p = 0;
#pragma unroll
        for (int i = 0; i < NL; ++i)
            p |= (uint64_t)bp_lds[r * NL + i] << (4 * i);
        packed_lds[r] = p;
    }
    __syncthreads();

    // ---- serial backtrack (address-independent LDS reads + 2-op extract) ----
    if (tid == 0) {
        int tag = vit_lds[BT - 1];
        for (int t = BT - 2; t >= 0; --t) {
            const uint64_t row = packed_lds[t];
            tag = (int)((row >> (4 * tag)) & 15u);
            vit_lds[t] = (uint8_t)tag;
        }
    }
    __syncthreads();

    // ---- stats + vit output ----
    float accv = 0.f, tpv = 0.f, tnv = 0.f, fpv = 0.f;
    for (int t = tid; t < BT; t += 256) {
        const int tg = vit_lds[t];
        const int lb = lab[t];
        const bool msk = t < sl;
        vit_out[(size_t)b * BT + t] = (float)tg;
        if (msk && tg == lb) accv += 1.f;
        if (lb > 0 && tg == lb) tpv += 1.f;
        if (lb > 0 && tg != lb) tnv += 1.f;
        if (msk && lb == 0 && tg > 0) fpv += 1.f;
    }
#pragma unroll
    for (int off = 32; off >= 1; off >>= 1) {
        accv += __shfl_xor(accv, off, 64);
        tpv  += __shfl_xor(tpv,  off, 64);
        tnv  += __shfl_xor(tnv,  off, 64);
        fpv  += __shfl_xor(fpv,  off, 64);
    }
    if (lane == 0) { xw[0][wv] = accv; xw[1][wv] = tpv; xw[2][wv] = tnv; xw[3][wv] = fpv; }
    __syncthreads();
    if (tid == 0) {
        stats[b * 8 + 2] = xw[0][0] + xw[0][1] + xw[0][2] + xw[0][3];
        stats[b * 8 + 3] = xw[1][0] + xw[1][1] + xw[1][2] + xw[1][3];
        stats[b * 8 + 4] = xw[2][0] + xw[2][1] + xw[2][2] + xw[2][3];
        stats[b * 8 + 5] = xw[3][0] + xw[3][1] + xw[3][2] + xw[3][3];
    }
}

// ---------------------------------------------------------------------------
// Kernel 3: reduce the 64 per-batch partials -> tp, tn, fp, loss, accuracy
// ---------------------------------------------------------------------------
__global__ __launch_bounds__(64) void finalize_kernel(
    const float* __restrict__ stats, const int* __restrict__ seqlen,
    float* __restrict__ out)
{
    const int lane = threadIdx.x;  // one lane per batch
    float score = stats[lane * 8 + 0];
    float logZ  = stats[lane * 8 + 1];
    float accv  = stats[lane * 8 + 2];
    float tpv   = stats[lane * 8 + 3];
    float tnv   = stats[lane * 8 + 4];
    float fpv   = stats[lane * 8 + 5];
    float nll   = logZ - score;
    float slf   = (float)seqlen[lane];
#pragma unroll
    for (int off = 32; off >= 1; off >>= 1) {
        nll  += __shfl_xor(nll,  off, 64);
        accv += __shfl_xor(accv, off, 64);
        tpv  += __shfl_xor(tpv,  off, 64);
        tnv  += __shfl_xor(tnv,  off, 64);
        fpv  += __shfl_xor(fpv,  off, 64);
        slf  += __shfl_xor(slf,  off, 64);
    }
    if (lane == 0) {
        out[NB * BT + 0] = tpv;
        out[NB * BT + 1] = tnv;
        out[NB * BT + 2] = fpv;
        out[NB * BT + 3] = nll / (float)NB;
        out[NB * BT + 4] = accv / slf;
    }
}

extern "C" void kernel_launch(void* const* d_in, const int* in_sizes, int n_in,
                              void* d_out, int out_size, void* d_ws, size_t ws_size,
                              hipStream_t stream)
{
    const float* x      = (const float*)d_in[0];
    const float* W      = (const float*)d_in[1];
    const float* bias   = (const float*)d_in[2];
    const float* trans  = (const float*)d_in[3];
    const int*   label  = (const int*)d_in[4];
    const int*   seqlen = (const int*)d_in[5];
    // d_in[6] = mask: recomputed from seqlen, unused

    float* out    = (float*)d_out;
    float* logits = (float*)d_ws;                  // 64*512*9 floats
    float* stats  = logits + (size_t)NB * BT * NL; // 64*8 floats

    gemm_kernel<<<NB * BT / 64, 256, 0, stream>>>(x, W, bias, logits);
    crf_kernel<<<NB, 256, 0, stream>>>(logits, trans, label, seqlen, out, stats);
    finalize_kernel<<<1, 64, 0, stream>>>(stats, seqlen, out);
}

// Round 5
// 218.124 us; speedup vs baseline: 1.7253x; 1.0703x over previous
//
#include <hip/hip_runtime.h>
#include <stdint.h>
#include <math.h>

#define NB 64      // batch
#define BT 512     // time steps
#define NH 768     // hidden
#define NL 9       // labels
#define PBT 528    // padded time rows in crf LDS

__device__ __forceinline__ float rlane(float v, int i) {
    return __int_as_float(__builtin_amdgcn_readlane(__float_as_int(v), i));
}

// ---------------------------------------------------------------------------
// Kernel 1: logits = x @ W + b.  Wave-per-row; W register-cached per lane
// (12 K-positions x 9 labels = 108 VGPRs, loaded ONCE); x loads are
// lane-consecutive float4 (1 KB/instr, fully coalesced); 2-deep row pipeline;
// butterfly reduce; static-index epilogue (no dynamic reg indexing).
// ---------------------------------------------------------------------------
__global__ __launch_bounds__(256, 2) void gemm_kernel(
    const float* __restrict__ x, const float* __restrict__ W,
    const float* __restrict__ bias, float* __restrict__ logits)
{
    const int lane   = threadIdx.x & 63;
    const int gwave  = (blockIdx.x * blockDim.x + threadIdx.x) >> 6;
    const int nw     = (gridDim.x * blockDim.x) >> 6;

    // one-time W preload: h = k*256 + lane*4 + u
    float wr[3][4][NL];
#pragma unroll
    for (int k = 0; k < 3; ++k)
#pragma unroll
        for (int u = 0; u < 4; ++u) {
            const int h = k * 256 + lane * 4 + u;
#pragma unroll
            for (int l = 0; l < NL; ++l) wr[k][u][l] = W[h * NL + l];
        }
    const float bj = bias[lane < NL ? lane : 0];

    const int nrows = NB * BT;
    int row = gwave;
    if (row >= nrows) return;

    const float4* xr = (const float4*)(x + (size_t)row * NH);
    float4 a0 = xr[lane], a1 = xr[64 + lane], a2 = xr[128 + lane];

    while (true) {
        const int nrow = row + nw;
        float4 b0, b1, b2;
        if (nrow < nrows) {   // prefetch next row while computing this one
            const float4* xn = (const float4*)(x + (size_t)nrow * NH);
            b0 = xn[lane]; b1 = xn[64 + lane]; b2 = xn[128 + lane];
        }

        float acc[NL];
#pragma unroll
        for (int l = 0; l < NL; ++l) {
            float s = a0.x * wr[0][0][l];
            s = fmaf(a0.y, wr[0][1][l], s);
            s = fmaf(a0.z, wr[0][2][l], s);
            s = fmaf(a0.w, wr[0][3][l], s);
            s = fmaf(a1.x, wr[1][0][l], s);
            s = fmaf(a1.y, wr[1][1][l], s);
            s = fmaf(a1.z, wr[1][2][l], s);
            s = fmaf(a1.w, wr[1][3][l], s);
            s = fmaf(a2.x, wr[2][0][l], s);
            s = fmaf(a2.y, wr[2][1][l], s);
            s = fmaf(a2.z, wr[2][2][l], s);
            s = fmaf(a2.w, wr[2][3][l], s);
            acc[l] = s;
        }
        // butterfly reduce across 64 lanes
#pragma unroll
        for (int off = 32; off >= 1; off >>= 1)
#pragma unroll
            for (int l = 0; l < NL; ++l) acc[l] += __shfl_xor(acc[l], off, 64);
        // static-index select: outv = acc[lane]
        float outv = acc[0];
#pragma unroll
        for (int l = 1; l < NL; ++l) outv = (lane == l) ? acc[l] : outv;
        if (lane < NL) logits[(size_t)row * NL + lane] = outv + bj;

        row = nrow;
        if (row >= nrows) break;
        a0 = b0; a1 = b1; a2 = b2;
    }
}

// ---------------------------------------------------------------------------
// Kernel 2: per-batch CRF. Block = 256 (4 waves).  (unchanged from round 4)
// ---------------------------------------------------------------------------
__global__ __launch_bounds__(256) void crf_kernel(
    const float* __restrict__ logits, const float* __restrict__ trans,
    const int* __restrict__ label, const int* __restrict__ seqlen,
    float* __restrict__ vit_out, float* __restrict__ stats)
{
    __shared__ __align__(16) float lg_lds[PBT * NL];   // padded, zeros past BT
    __shared__ float    val_lds[BT * NL];              // viterbi alpha vectors
    __shared__ float    trans_lds[NL * NL];
    __shared__ uint8_t  bp_lds[(BT - 1) * NL];
    __shared__ uint64_t packed_lds[BT - 1];
    __shared__ uint8_t  vit_lds[BT];
    __shared__ float    xw[4][4];

    const int b    = blockIdx.x;
    const int tid  = threadIdx.x;
    const int lane = tid & 63;
    const int wv   = tid >> 6;
    const int sl   = seqlen[b];
    const float* lg  = logits + (size_t)b * BT * NL;
    const int*   lab = label + (size_t)b * BT;

    // stage logits (float4) + zero padding + transitions
    {
        const float4* src = (const float4*)lg;
        float4* dst = (float4*)lg_lds;
        for (int idx = tid; idx < BT * NL / 4; idx += 256) dst[idx] = src[idx];
        for (int idx = BT * NL + tid; idx < PBT * NL; idx += 256) lg_lds[idx] = 0.f;
        if (tid < NL * NL) trans_lds[tid] = trans[tid];
    }
    __syncthreads();

    if (wv == 0) {
        // ---- logZ scan, scaled-exp domain ----
        const int j = lane < NL ? lane : 0;
        float E[NL];
#pragma unroll
        for (int i = 0; i < NL; ++i) E[i] = __expf(trans_lds[i * NL + j]) * 0.125f;
        float A = __expf(lg_lds[j]);
        int lc = 0;
        for (int tb = 1; tb < BT + 8; tb += 8) {
            float P[8];
#pragma unroll
            for (int s = 0; s < 8; ++s) P[s] = __expf(lg_lds[(tb + s) * NL + j]);
#pragma unroll
            for (int s = 0; s < 8; ++s) {
                const int t = tb + s;
                const float r0 = rlane(A, 0), r1 = rlane(A, 1), r2 = rlane(A, 2),
                            r3 = rlane(A, 3), r4 = rlane(A, 4), r5 = rlane(A, 5),
                            r6 = rlane(A, 6), r7 = rlane(A, 7), r8 = rlane(A, 8);
                float p0 = r0 * E[0]; p0 = fmaf(r1, E[1], p0); p0 = fmaf(r2, E[2], p0);
                float p1 = r3 * E[3]; p1 = fmaf(r4, E[4], p1); p1 = fmaf(r5, E[5], p1);
                float p2 = r6 * E[6]; p2 = fmaf(r7, E[7], p2); p2 = fmaf(r8, E[8], p2);
                const float An = ((p0 + p1) + p2) * P[s];
                A = (t < sl) ? An : A;
            }
            // exact pow2 renorm: m is positive & normal here.
            const float m = fmaxf(fmaxf(
                fmaxf(fmaxf(rlane(A, 0), rlane(A, 1)), fmaxf(rlane(A, 2), rlane(A, 3))),
                fmaxf(fmaxf(rlane(A, 4), rlane(A, 5)), fmaxf(rlane(A, 6), rlane(A, 7)))),
                rlane(A, 8));
            const int ex = (int)((__float_as_uint(m) >> 23) & 0xFFu) - 126; // frexp exp
            const float sc = __uint_as_float((uint32_t)(127 - ex) << 23);   // 2^-ex
            A *= sc;
            lc += ex;
        }
        const float sum = ((rlane(A, 0) + rlane(A, 1)) + (rlane(A, 2) + rlane(A, 3))) +
                          ((rlane(A, 4) + rlane(A, 5)) + (rlane(A, 6) + rlane(A, 7))) +
                          rlane(A, 8);
        const float logZ = logf(sum) +
            ((float)lc + 3.0f * (float)(sl - 1)) * 0.6931471805599453f;
        if (lane == 0) stats[b * 8 + 1] = logZ;
    } else if (wv == 1) {
        // ---- viterbi value scan; alpha vectors to LDS, argmax deferred ----
        const int j = lane < NL ? lane : 0;
        float tc[NL];
#pragma unroll
        for (int i = 0; i < NL; ++i) tc[i] = trans_lds[i * NL + j];
        float v = lg_lds[j];
        if (lane < NL) val_lds[j] = v;
        for (int tb = 1; tb < BT + 8; tb += 8) {
            float lv[8];
#pragma unroll
            for (int s = 0; s < 8; ++s) lv[s] = lg_lds[(tb + s) * NL + j];
#pragma unroll
            for (int s = 0; s < 8; ++s) {
                const int t = tb + s;
                const float r0 = rlane(v, 0), r1 = rlane(v, 1), r2 = rlane(v, 2),
                            r3 = rlane(v, 3), r4 = rlane(v, 4), r5 = rlane(v, 5),
                            r6 = rlane(v, 6), r7 = rlane(v, 7), r8 = rlane(v, 8);
                const float c0 = r0 + tc[0], c1 = r1 + tc[1], c2 = r2 + tc[2],
                            c3 = r3 + tc[3], c4 = r4 + tc[4], c5 = r5 + tc[5],
                            c6 = r6 + tc[6], c7 = r7 + tc[7], c8 = r8 + tc[8];
                const float m = fmaxf(fmaxf(fmaxf(fmaxf(c0, c1), c2),
                                            fmaxf(fmaxf(c3, c4), c5)),
                                      fmaxf(fmaxf(c6, c7), c8));
                const float nv = m + lv[s];
                v = (t < sl) ? nv : v;
                if (lane < NL && t < BT) val_lds[t * NL + lane] = v;
            }
        }
        // last tag = first-argmax(alphaT)
        const float r0 = rlane(v, 0), r1 = rlane(v, 1), r2 = rlane(v, 2),
                    r3 = rlane(v, 3), r4 = rlane(v, 4), r5 = rlane(v, 5),
                    r6 = rlane(v, 6), r7 = rlane(v, 7), r8 = rlane(v, 8);
        const float m = fmaxf(fmaxf(fmaxf(fmaxf(r0, r1), r2),
                                    fmaxf(fmaxf(r3, r4), r5)),
                              fmaxf(fmaxf(r6, r7), r8));
        const int last = (r0 == m) ? 0 : (r1 == m) ? 1 : (r2 == m) ? 2 :
                         (r3 == m) ? 3 : (r4 == m) ? 4 : (r5 == m) ? 5 :
                         (r6 == m) ? 6 : (r7 == m) ? 7 : 8;
        if (lane == 0) vit_lds[BT - 1] = (uint8_t)last;
    } else if (wv == 2) {
        // ---- gold-path score ----
        float s = 0.f;
        for (int t = lane; t < BT; t += 64) {
            const int lb = lab[t];
            if (t < sl) {
                s += lg_lds[t * NL + lb];
                if (t >= 1) s += trans_lds[lab[t - 1] * NL + lb];
            }
        }
#pragma unroll
        for (int off = 32; off >= 1; off >>= 1) s += __shfl_xor(s, off, 64);
        if (lane == 0) stats[b * 8 + 0] = s;
    }
    __syncthreads();

    // ---- recompute backpointers in parallel (bit-exact first-max) ----
    for (int idx = tid; idx < (BT - 1) * NL; idx += 256) {
        const int tm1 = idx / NL;
        const int jj  = idx - tm1 * NL;
        const int t   = tm1 + 1;
        int bi;
        if (t >= sl) bi = jj;
        else {
            float best = val_lds[tm1 * NL] + trans_lds[jj];
            bi = 0;
#pragma unroll
            for (int i = 1; i < NL; ++i) {
                const float c = val_lds[tm1 * NL + i] + trans_lds[i * NL + jj];
                if (c > best) { best = c; bi = i; }
            }
        }
        bp_lds[idx] = (uint8_t)bi;
    }
    __syncthreads();

    // ---- pack bp rows: 9 x 4 bits -> u64 ----
    for (int r = tid; r < BT - 1; r += 256) {
        uint64_t p = 0;
#pragma unroll
        for (int i = 0; i < NL; ++i)
            p |= (uint64_t)bp_lds[r * NL + i] << (4 * i);
        packed_lds[r] = p;
    }
    __syncthreads();

    // ---- serial backtrack (address-independent LDS reads + 2-op extract) ----
    if (tid == 0) {
        int tag = vit_lds[BT - 1];
        for (int t = BT - 2; t >= 0; --t) {
            const uint64_t row = packed_lds[t];
            tag = (int)((row >> (4 * tag)) & 15u);
            vit_lds[t] = (uint8_t)tag;
        }
    }
    __syncthreads();

    // ---- stats + vit output ----
    float accv = 0.f, tpv = 0.f, tnv = 0.f, fpv = 0.f;
    for (int t = tid; t < BT; t += 256) {
        const int tg = vit_lds[t];
        const int lb = lab[t];
        const bool msk = t < sl;
        vit_out[(size_t)b * BT + t] = (float)tg;
        if (msk && tg == lb) accv += 1.f;
        if (lb > 0 && tg == lb) tpv += 1.f;
        if (lb > 0 && tg != lb) tnv += 1.f;
        if (msk && lb == 0 && tg > 0) fpv += 1.f;
    }
#pragma unroll
    for (int off = 32; off >= 1; off >>= 1) {
        accv += __shfl_xor(accv, off, 64);
        tpv  += __shfl_xor(tpv,  off, 64);
        tnv  += __shfl_xor(tnv,  off, 64);
        fpv  += __shfl_xor(fpv,  off, 64);
    }
    if (lane == 0) { xw[0][wv] = accv; xw[1][wv] = tpv; xw[2][wv] = tnv; xw[3][wv] = fpv; }
    __syncthreads();
    if (tid == 0) {
        stats[b * 8 + 2] = xw[0][0] + xw[0][1] + xw[0][2] + xw[0][3];
        stats[b * 8 + 3] = xw[1][0] + xw[1][1] + xw[1][2] + xw[1][3];
        stats[b * 8 + 4] = xw[2][0] + xw[2][1] + xw[2][2] + xw[2][3];
        stats[b * 8 + 5] = xw[3][0] + xw[3][1] + xw[3][2] + xw[3][3];
    }
}

// ---------------------------------------------------------------------------
// Kernel 3: reduce the 64 per-batch partials -> tp, tn, fp, loss, accuracy
// ---------------------------------------------------------------------------
__global__ __launch_bounds__(64) void finalize_kernel(
    const float* __restrict__ stats, const int* __restrict__ seqlen,
    float* __restrict__ out)
{
    const int lane = threadIdx.x;  // one lane per batch
    float score = stats[lane * 8 + 0];
    float logZ  = stats[lane * 8 + 1];
    float accv  = stats[lane * 8 + 2];
    float tpv   = stats[lane * 8 + 3];
    float tnv   = stats[lane * 8 + 4];
    float fpv   = stats[lane * 8 + 5];
    float nll   = logZ - score;
    float slf   = (float)seqlen[lane];
#pragma unroll
    for (int off = 32; off >= 1; off >>= 1) {
        nll  += __shfl_xor(nll,  off, 64);
        accv += __shfl_xor(accv, off, 64);
        tpv  += __shfl_xor(tpv,  off, 64);
        tnv  += __shfl_xor(tnv,  off, 64);
        fpv  += __shfl_xor(fpv,  off, 64);
        slf  += __shfl_xor(slf,  off, 64);
    }
    if (lane == 0) {
        out[NB * BT + 0] = tpv;
        out[NB * BT + 1] = tnv;
        out[NB * BT + 2] = fpv;
        out[NB * BT + 3] = nll / (float)NB;
        out[NB * BT + 4] = accv / slf;
    }
}

extern "C" void kernel_launch(void* const* d_in, const int* in_sizes, int n_in,
                              void* d_out, int out_size, void* d_ws, size_t ws_size,
                              hipStream_t stream)
{
    const float* x      = (const float*)d_in[0];
    const float* W      = (const float*)d_in[1];
    const float* bias   = (const float*)d_in[2];
    const float* trans  = (const float*)d_in[3];
    const int*   label  = (const int*)d_in[4];
    const int*   seqlen = (const int*)d_in[5];
    // d_in[6] = mask: recomputed from seqlen, unused

    float* out    = (float*)d_out;
    float* logits = (float*)d_ws;                  // 64*512*9 floats
    float* stats  = logits + (size_t)NB * BT * NL; // 64*8 floats

    gemm_kernel<<<768, 256, 0, stream>>>(x, W, bias, logits);
    crf_kernel<<<NB, 256, 0, stream>>>(logits, trans, label, seqlen, out, stats);
    finalize_kernel<<<1, 64, 0, stream>>>(stats, seqlen, out);
}

// Round 6
// 214.039 us; speedup vs baseline: 1.7583x; 1.0191x over previous
//
#include <hip/hip_runtime.h>
#include <stdint.h>
#include <math.h>

#define NB 64      // batch
#define BT 512     // time steps
#define NH 768     // hidden
#define NL 9       // labels
#define PBT 528    // padded time rows in crf LDS

__device__ __forceinline__ float rlane(float v, int i) {
    return __int_as_float(__builtin_amdgcn_readlane(__float_as_int(v), i));
}

// DPP-based cross-lane add: v += dpp_move(v); runs on VALU, NOT the DS pipe.
template<int CTRL, int RM>
__device__ __forceinline__ float dppadd(float v) {
    const int t = __builtin_amdgcn_update_dpp(0, __float_as_int(v), CTRL, RM, 0xf, true);
    return v + __int_as_float(t);
}

// full 64-lane sum -> uniform scalar (read from lane 63)
__device__ __forceinline__ float wave_sum_dpp(float v) {
    v = dppadd<0x111, 0xf>(v);   // row_shr:1
    v = dppadd<0x112, 0xf>(v);   // row_shr:2
    v = dppadd<0x114, 0xf>(v);   // row_shr:4
    v = dppadd<0x118, 0xf>(v);   // row_shr:8  -> lane 15 of each row16 = row sum
    v = dppadd<0x142, 0xa>(v);   // row_bcast:15 into rows 1,3
    v = dppadd<0x143, 0xc>(v);   // row_bcast:31 into rows 2,3 -> lane 63 = total
    return rlane(v, 63);
}

// ---------------------------------------------------------------------------
// Kernel 1: logits = x @ W + b.  Wave-per-row; W register-cached per lane
// (108 VGPRs, loaded ONCE); coalesced float4 x loads; 2-deep row pipeline;
// DPP reduction (no DS-pipe bpermutes — R5 was DS-bound at 54 shuffles/row).
// ---------------------------------------------------------------------------
__global__ __launch_bounds__(256, 2) void gemm_kernel(
    const float* __restrict__ x, const float* __restrict__ W,
    const float* __restrict__ bias, float* __restrict__ logits)
{
    const int lane   = threadIdx.x & 63;
    const int gwave  = (blockIdx.x * blockDim.x + threadIdx.x) >> 6;
    const int nw     = (gridDim.x * blockDim.x) >> 6;

    // one-time W preload: h = k*256 + lane*4 + u
    float wr[3][4][NL];
#pragma unroll
    for (int k = 0; k < 3; ++k)
#pragma unroll
        for (int u = 0; u < 4; ++u) {
            const int h = k * 256 + lane * 4 + u;
#pragma unroll
            for (int l = 0; l < NL; ++l) wr[k][u][l] = W[h * NL + l];
        }
    const float bj = bias[lane < NL ? lane : 0];

    const int nrows = NB * BT;
    int row = gwave;
    if (row >= nrows) return;

    const float4* xr = (const float4*)(x + (size_t)row * NH);
    float4 a0 = xr[lane], a1 = xr[64 + lane], a2 = xr[128 + lane];

    while (true) {
        const int nrow = row + nw;
        float4 b0, b1, b2;
        if (nrow < nrows) {   // prefetch next row while computing this one
            const float4* xn = (const float4*)(x + (size_t)nrow * NH);
            b0 = xn[lane]; b1 = xn[64 + lane]; b2 = xn[128 + lane];
        }

        float acc[NL];
#pragma unroll
        for (int l = 0; l < NL; ++l) {
            float s = a0.x * wr[0][0][l];
            s = fmaf(a0.y, wr[0][1][l], s);
            s = fmaf(a0.z, wr[0][2][l], s);
            s = fmaf(a0.w, wr[0][3][l], s);
            s = fmaf(a1.x, wr[1][0][l], s);
            s = fmaf(a1.y, wr[1][1][l], s);
            s = fmaf(a1.z, wr[1][2][l], s);
            s = fmaf(a1.w, wr[1][3][l], s);
            s = fmaf(a2.x, wr[2][0][l], s);
            s = fmaf(a2.y, wr[2][1][l], s);
            s = fmaf(a2.z, wr[2][2][l], s);
            s = fmaf(a2.w, wr[2][3][l], s);
            acc[l] = s;
        }
        // DPP wave-sum per label -> 9 uniform scalars (VALU only, no DS)
        float sum[NL];
#pragma unroll
        for (int l = 0; l < NL; ++l) sum[l] = wave_sum_dpp(acc[l]);
        // lane j (<9) stores sum[j]: static-index select chain
        float outv = sum[0];
#pragma unroll
        for (int l = 1; l < NL; ++l) outv = (lane == l) ? sum[l] : outv;
        if (lane < NL) logits[(size_t)row * NL + lane] = outv + bj;

        row = nrow;
        if (row >= nrows) break;
        a0 = b0; a1 = b1; a2 = b2;
    }
}

// ---------------------------------------------------------------------------
// Kernel 2: per-batch CRF. Block = 256 (4 waves).  (unchanged — validated)
// ---------------------------------------------------------------------------
__global__ __launch_bounds__(256) void crf_kernel(
    const float* __restrict__ logits, const float* __restrict__ trans,
    const int* __restrict__ label, const int* __restrict__ seqlen,
    float* __restrict__ vit_out, float* __restrict__ stats)
{
    __shared__ __align__(16) float lg_lds[PBT * NL];   // padded, zeros past BT
    __shared__ float    val_lds[BT * NL];              // viterbi alpha vectors
    __shared__ float    trans_lds[NL * NL];
    __shared__ uint8_t  bp_lds[(BT - 1) * NL];
    __shared__ uint64_t packed_lds[BT - 1];
    __shared__ uint8_t  vit_lds[BT];
    __shared__ float    xw[4][4];

    const int b    = blockIdx.x;
    const int tid  = threadIdx.x;
    const int lane = tid & 63;
    const int wv   = tid >> 6;
    const int sl   = seqlen[b];
    const float* lg  = logits + (size_t)b * BT * NL;
    const int*   lab = label + (size_t)b * BT;

    // stage logits (float4) + zero padding + transitions
    {
        const float4* src = (const float4*)lg;
        float4* dst = (float4*)lg_lds;
        for (int idx = tid; idx < BT * NL / 4; idx += 256) dst[idx] = src[idx];
        for (int idx = BT * NL + tid; idx < PBT * NL; idx += 256) lg_lds[idx] = 0.f;
        if (tid < NL * NL) trans_lds[tid] = trans[tid];
    }
    __syncthreads();

    if (wv == 0) {
        // ---- logZ scan, scaled-exp domain ----
        const int j = lane < NL ? lane : 0;
        float E[NL];
#pragma unroll
        for (int i = 0; i < NL; ++i) E[i] = __expf(trans_lds[i * NL + j]) * 0.125f;
        float A = __expf(lg_lds[j]);
        int lc = 0;
        for (int tb = 1; tb < BT + 8; tb += 8) {
            float P[8];
#pragma unroll
            for (int s = 0; s < 8; ++s) P[s] = __expf(lg_lds[(tb + s) * NL + j]);
#pragma unroll
            for (int s = 0; s < 8; ++s) {
                const int t = tb + s;
                const float r0 = rlane(A, 0), r1 = rlane(A, 1), r2 = rlane(A, 2),
                            r3 = rlane(A, 3), r4 = rlane(A, 4), r5 = rlane(A, 5),
                            r6 = rlane(A, 6), r7 = rlane(A, 7), r8 = rlane(A, 8);
                float p0 = r0 * E[0]; p0 = fmaf(r1, E[1], p0); p0 = fmaf(r2, E[2], p0);
                float p1 = r3 * E[3]; p1 = fmaf(r4, E[4], p1); p1 = fmaf(r5, E[5], p1);
                float p2 = r6 * E[6]; p2 = fmaf(r7, E[7], p2); p2 = fmaf(r8, E[8], p2);
                const float An = ((p0 + p1) + p2) * P[s];
                A = (t < sl) ? An : A;
            }
            // exact pow2 renorm: m is positive & normal here.
            const float m = fmaxf(fmaxf(
                fmaxf(fmaxf(rlane(A, 0), rlane(A, 1)), fmaxf(rlane(A, 2), rlane(A, 3))),
                fmaxf(fmaxf(rlane(A, 4), rlane(A, 5)), fmaxf(rlane(A, 6), rlane(A, 7)))),
                rlane(A, 8));
            const int ex = (int)((__float_as_uint(m) >> 23) & 0xFFu) - 126; // frexp exp
            const float sc = __uint_as_float((uint32_t)(127 - ex) << 23);   // 2^-ex
            A *= sc;
            lc += ex;
        }
        const float sum = ((rlane(A, 0) + rlane(A, 1)) + (rlane(A, 2) + rlane(A, 3))) +
                          ((rlane(A, 4) + rlane(A, 5)) + (rlane(A, 6) + rlane(A, 7))) +
                          rlane(A, 8);
        const float logZ = logf(sum) +
            ((float)lc + 3.0f * (float)(sl - 1)) * 0.6931471805599453f;
        if (lane == 0) stats[b * 8 + 1] = logZ;
    } else if (wv == 1) {
        // ---- viterbi value scan; alpha vectors to LDS, argmax deferred ----
        const int j = lane < NL ? lane : 0;
        float tc[NL];
#pragma unroll
        for (int i = 0; i < NL; ++i) tc[i] = trans_lds[i * NL + j];
        float v = lg_lds[j];
        if (lane < NL) val_lds[j] = v;
        for (int tb = 1; tb < BT + 8; tb += 8) {
            float lv[8];
#pragma unroll
            for (int s = 0; s < 8; ++s) lv[s] = lg_lds[(tb + s) * NL + j];
#pragma unroll
            for (int s = 0; s < 8; ++s) {
                const int t = tb + s;
                const float r0 = rlane(v, 0), r1 = rlane(v, 1), r2 = rlane(v, 2),
                            r3 = rlane(v, 3), r4 = rlane(v, 4), r5 = rlane(v, 5),
                            r6 = rlane(v, 6), r7 = rlane(v, 7), r8 = rlane(v, 8);
                const float c0 = r0 + tc[0], c1 = r1 + tc[1], c2 = r2 + tc[2],
                            c3 = r3 + tc[3], c4 = r4 + tc[4], c5 = r5 + tc[5],
                            c6 = r6 + tc[6], c7 = r7 + tc[7], c8 = r8 + tc[8];
                const float m = fmaxf(fmaxf(fmaxf(fmaxf(c0, c1), c2),
                                            fmaxf(fmaxf(c3, c4), c5)),
                                      fmaxf(fmaxf(c6, c7), c8));
                const float nv = m + lv[s];
                v = (t < sl) ? nv : v;
                if (lane < NL && t < BT) val_lds[t * NL + lane] = v;
            }
        }
        // last tag = first-argmax(alphaT)
        const float r0 = rlane(v, 0), r1 = rlane(v, 1), r2 = rlane(v, 2),
                    r3 = rlane(v, 3), r4 = rlane(v, 4), r5 = rlane(v, 5),
                    r6 = rlane(v, 6), r7 = rlane(v, 7), r8 = rlane(v, 8);
        const float m = fmaxf(fmaxf(fmaxf(fmaxf(r0, r1), r2),
                                    fmaxf(fmaxf(r3, r4), r5)),
                              fmaxf(fmaxf(r6, r7), r8));
        const int last = (r0 == m) ? 0 : (r1 == m) ? 1 : (r2 == m) ? 2 :
                         (r3 == m) ? 3 : (r4 == m) ? 4 : (r5 == m) ? 5 :
                         (r6 == m) ? 6 : (r7 == m) ? 7 : 8;
        if (lane == 0) vit_lds[BT - 1] = (uint8_t)last;
    } else if (wv == 2) {
        // ---- gold-path score ----
        float s = 0.f;
        for (int t = lane; t < BT; t += 64) {
            const int lb = lab[t];
            if (t < sl) {
                s += lg_lds[t * NL + lb];
                if (t >= 1) s += trans_lds[lab[t - 1] * NL + lb];
            }
        }
#pragma unroll
        for (int off = 32; off >= 1; off >>= 1) s += __shfl_xor(s, off, 64);
        if (lane == 0) stats[b * 8 + 0] = s;
    }
    __syncthreads();

    // ---- recompute backpointers in parallel (bit-exact first-max) ----
    for (int idx = tid; idx < (BT - 1) * NL; idx += 256) {
        const int tm1 = idx / NL;
        const int jj  = idx - tm1 * NL;
        const int t   = tm1 + 1;
        int bi;
        if (t >= sl) bi = jj;
        else {
            float best = val_lds[tm1 * NL] + trans_lds[jj];
            bi = 0;
#pragma unroll
            for (int i = 1; i < NL; ++i) {
                const float c = val_lds[tm1 * NL + i] + trans_lds[i * NL + jj];
                if (c > best) { best = c; bi = i; }
            }
        }
        bp_lds[idx] = (uint8_t)bi;
    }
    __syncthreads();

    // ---- pack bp rows: 9 x 4 bits -> u64 ----
    for (int r = tid; r < BT - 1; r += 256) {
        uint64_t p = 0;
#pragma unroll
        for (int i = 0; i < NL; ++i)
            p |= (uint64_t)bp_lds[r * NL + i] << (4 * i);
        packed_lds[r] = p;
    }
    __syncthreads();

    // ---- serial backtrack (address-independent LDS reads + 2-op extract) ----
    if (tid == 0) {
        int tag = vit_lds[BT - 1];
        for (int t = BT - 2; t >= 0; --t) {
            const uint64_t row = packed_lds[t];
            tag = (int)((row >> (4 * tag)) & 15u);
            vit_lds[t] = (uint8_t)tag;
        }
    }
    __syncthreads();

    // ---- stats + vit output ----
    float accv = 0.f, tpv = 0.f, tnv = 0.f, fpv = 0.f;
    for (int t = tid; t < BT; t += 256) {
        const int tg = vit_lds[t];
        const int lb = lab[t];
        const bool msk = t < sl;
        vit_out[(size_t)b * BT + t] = (float)tg;
        if (msk && tg == lb) accv += 1.f;
        if (lb > 0 && tg == lb) tpv += 1.f;
        if (lb > 0 && tg != lb) tnv += 1.f;
        if (msk && lb == 0 && tg > 0) fpv += 1.f;
    }
#pragma unroll
    for (int off = 32; off >= 1; off >>= 1) {
        accv += __shfl_xor(accv, off, 64);
        tpv  += __shfl_xor(tpv,  off, 64);
        tnv  += __shfl_xor(tnv,  off, 64);
        fpv  += __shfl_xor(fpv,  off, 64);
    }
    if (lane == 0) { xw[0][wv] = accv; xw[1][wv] = tpv; xw[2][wv] = tnv; xw[3][wv] = fpv; }
    __syncthreads();
    if (tid == 0) {
        stats[b * 8 + 2] = xw[0][0] + xw[0][1] + xw[0][2] + xw[0][3];
        stats[b * 8 + 3] = xw[1][0] + xw[1][1] + xw[1][2] + xw[1][3];
        stats[b * 8 + 4] = xw[2][0] + xw[2][1] + xw[2][2] + xw[2][3];
        stats[b * 8 + 5] = xw[3][0] + xw[3][1] + xw[3][2] + xw[3][3];
    }
}

// ---------------------------------------------------------------------------
// Kernel 3: reduce the 64 per-batch partials -> tp, tn, fp, loss, accuracy
// ---------------------------------------------------------------------------
__global__ __launch_bounds__(64) void finalize_kernel(
    const float* __restrict__ stats, const int* __restrict__ seqlen,
    float* __restrict__ out)
{
    const int lane = threadIdx.x;  // one lane per batch
    float score = stats[lane * 8 + 0];
    float logZ  = stats[lane * 8 + 1];
    float accv  = stats[lane * 8 + 2];
    float tpv   = stats[lane * 8 + 3];
    float tnv   = stats[lane * 8 + 4];
    float fpv   = stats[lane * 8 + 5];
    float nll   = logZ - score;
    float slf   = (float)seqlen[lane];
#pragma unroll
    for (int off = 32; off >= 1; off >>= 1) {
        nll  += __shfl_xor(nll,  off, 64);
        accv += __shfl_xor(accv, off, 64);
        tpv  += __shfl_xor(tpv,  off, 64);
        tnv  += __shfl_xor(tnv,  off, 64);
        fpv  += __shfl_xor(fpv,  off, 64);
        slf  += __shfl_xor(slf,  off, 64);
    }
    if (lane == 0) {
        out[NB * BT + 0] = tpv;
        out[NB * BT + 1] = tnv;
        out[NB * BT + 2] = fpv;
        out[NB * BT + 3] = nll / (float)NB;
        out[NB * BT + 4] = accv / slf;
    }
}

extern "C" void kernel_launch(void* const* d_in, const int* in_sizes, int n_in,
                              void* d_out, int out_size, void* d_ws, size_t ws_size,
                              hipStream_t stream)
{
    const float* x      = (const float*)d_in[0];
    const float* W      = (const float*)d_in[1];
    const float* bias   = (const float*)d_in[2];
    const float* trans  = (const float*)d_in[3];
    const int*   label  = (const int*)d_in[4];
    const int*   seqlen = (const int*)d_in[5];
    // d_in[6] = mask: recomputed from seqlen, unused

    float* out    = (float*)d_out;
    float* logits = (float*)d_ws;                  // 64*512*9 floats
    float* stats  = logits + (size_t)NB * BT * NL; // 64*8 floats

    gemm_kernel<<<768, 256, 0, stream>>>(x, W, bias, logits);
    crf_kernel<<<NB, 256, 0, stream>>>(logits, trans, label, seqlen, out, stats);
    finalize_kernel<<<1, 64, 0, stream>>>(stats, seqlen, out);
}

// Round 7
// 212.474 us; speedup vs baseline: 1.7712x; 1.0074x over previous
//
#include <hip/hip_runtime.h>
#include <stdint.h>
#include <math.h>

#define NB 64      // batch
#define BT 512     // time steps
#define NH 768     // hidden
#define NL 9       // labels
#define PBT 528    // padded time rows in crf LDS
#define PADW 772   // padded W row stride (floats): (l*772+h)%32 spreads banks

__device__ __forceinline__ float rlane(float v, int i) {
    return __int_as_float(__builtin_amdgcn_readlane(__float_as_int(v), i));
}

// DPP-based cross-lane add: v += dpp_move(v); runs on VALU, NOT the DS pipe.
template<int CTRL, int RM>
__device__ __forceinline__ float dppadd(float v) {
    const int t = __builtin_amdgcn_update_dpp(0, __float_as_int(v), CTRL, RM, 0xf, true);
    return v + __int_as_float(t);
}

// full 64-lane sum -> uniform scalar (read from lane 63)
__device__ __forceinline__ float wave_sum_dpp(float v) {
    v = dppadd<0x111, 0xf>(v);   // row_shr:1
    v = dppadd<0x112, 0xf>(v);   // row_shr:2
    v = dppadd<0x114, 0xf>(v);   // row_shr:4
    v = dppadd<0x118, 0xf>(v);   // row_shr:8  -> lane 15 of each row16 = row sum
    v = dppadd<0x142, 0xa>(v);   // row_bcast:15 into rows 1,3
    v = dppadd<0x143, 0xc>(v);   // row_bcast:31 into rows 2,3 -> lane 63 = total
    return rlane(v, 63);
}

// ---------------------------------------------------------------------------
// Kernel 1: logits = x @ W + b.  Wave-per-row; W register cache now filled
// from an LDS-transposed copy via conflict-free ds_read_b128 (the old direct
// global preload had 144 B lane stride = 64 cache lines per instr -> ~7k cyc
// per wave).  Coalesced float4 x loads; 2-deep row pipeline; DPP reduce.
// Grid 512 blocks = 2048 waves = one resident generation, 16 rows/wave.
// ---------------------------------------------------------------------------
__global__ __launch_bounds__(256, 2) void gemm_kernel(
    const float* __restrict__ x, const float* __restrict__ W,
    const float* __restrict__ bias, float* __restrict__ logits)
{
    __shared__ float wT[NL * PADW];   // 27.8 KB: W transposed [l][h], padded

    const int tid  = threadIdx.x;
    const int lane = tid & 63;

    // stage W transposed into LDS (coalesced global reads, one-time)
    for (int i = tid; i < NH * NL; i += 256) {
        const int h = i / NL, l = i - h * NL;
        wT[l * PADW + h] = W[i];
    }
    __syncthreads();

    // per-lane register cache: 27 conflict-free ds_read_b128
    float wr[3][NL][4];
#pragma unroll
    for (int k = 0; k < 3; ++k)
#pragma unroll
        for (int l = 0; l < NL; ++l) {
            const float4 w4 = *(const float4*)&wT[l * PADW + k * 256 + lane * 4];
            wr[k][l][0] = w4.x; wr[k][l][1] = w4.y;
            wr[k][l][2] = w4.z; wr[k][l][3] = w4.w;
        }
    const float bj = bias[lane < NL ? lane : 0];

    const int gwave = (blockIdx.x * blockDim.x + tid) >> 6;
    const int nw    = (gridDim.x * blockDim.x) >> 6;
    const int nrows = NB * BT;
    int row = gwave;
    if (row >= nrows) return;

    const float4* xr = (const float4*)(x + (size_t)row * NH);
    float4 a0 = xr[lane], a1 = xr[64 + lane], a2 = xr[128 + lane];

    while (true) {
        const int nrow = row + nw;
        float4 b0, b1, b2;
        if (nrow < nrows) {   // prefetch next row while computing this one
            const float4* xn = (const float4*)(x + (size_t)nrow * NH);
            b0 = xn[lane]; b1 = xn[64 + lane]; b2 = xn[128 + lane];
        }

        float acc[NL];
#pragma unroll
        for (int l = 0; l < NL; ++l) {
            float s = a0.x * wr[0][l][0];
            s = fmaf(a0.y, wr[0][l][1], s);
            s = fmaf(a0.z, wr[0][l][2], s);
            s = fmaf(a0.w, wr[0][l][3], s);
            s = fmaf(a1.x, wr[1][l][0], s);
            s = fmaf(a1.y, wr[1][l][1], s);
            s = fmaf(a1.z, wr[1][l][2], s);
            s = fmaf(a1.w, wr[1][l][3], s);
            s = fmaf(a2.x, wr[2][l][0], s);
            s = fmaf(a2.y, wr[2][l][1], s);
            s = fmaf(a2.z, wr[2][l][2], s);
            s = fmaf(a2.w, wr[2][l][3], s);
            acc[l] = s;
        }
        // DPP wave-sum per label -> 9 uniform scalars (VALU only, no DS)
        float sum[NL];
#pragma unroll
        for (int l = 0; l < NL; ++l) sum[l] = wave_sum_dpp(acc[l]);
        // lane j (<9) stores sum[j]: static-index select chain
        float outv = sum[0];
#pragma unroll
        for (int l = 1; l < NL; ++l) outv = (lane == l) ? sum[l] : outv;
        if (lane < NL) logits[(size_t)row * NL + lane] = outv + bj;

        row = nrow;
        if (row >= nrows) break;
        a0 = b0; a1 = b1; a2 = b2;
    }
}

// ---------------------------------------------------------------------------
// Kernel 2: per-batch CRF. Block = 256 (4 waves).  (unchanged — validated)
// ---------------------------------------------------------------------------
__global__ __launch_bounds__(256) void crf_kernel(
    const float* __restrict__ logits, const float* __restrict__ trans,
    const int* __restrict__ label, const int* __restrict__ seqlen,
    float* __restrict__ vit_out, float* __restrict__ stats)
{
    __shared__ __align__(16) float lg_lds[PBT * NL];   // padded, zeros past BT
    __shared__ float    val_lds[BT * NL];              // viterbi alpha vectors
    __shared__ float    trans_lds[NL * NL];
    __shared__ uint8_t  bp_lds[(BT - 1) * NL];
    __shared__ uint64_t packed_lds[BT - 1];
    __shared__ uint8_t  vit_lds[BT];
    __shared__ float    xw[4][4];

    const int b    = blockIdx.x;
    const int tid  = threadIdx.x;
    const int lane = tid & 63;
    const int wv   = tid >> 6;
    const int sl   = seqlen[b];
    const float* lg  = logits + (size_t)b * BT * NL;
    const int*   lab = label + (size_t)b * BT;

    // stage logits (float4) + zero padding + transitions
    {
        const float4* src = (const float4*)lg;
        float4* dst = (float4*)lg_lds;
        for (int idx = tid; idx < BT * NL / 4; idx += 256) dst[idx] = src[idx];
        for (int idx = BT * NL + tid; idx < PBT * NL; idx += 256) lg_lds[idx] = 0.f;
        if (tid < NL * NL) trans_lds[tid] = trans[tid];
    }
    __syncthreads();

    if (wv == 0) {
        // ---- logZ scan, scaled-exp domain ----
        const int j = lane < NL ? lane : 0;
        float E[NL];
#pragma unroll
        for (int i = 0; i < NL; ++i) E[i] = __expf(trans_lds[i * NL + j]) * 0.125f;
        float A = __expf(lg_lds[j]);
        int lc = 0;
        for (int tb = 1; tb < BT + 8; tb += 8) {
            float P[8];
#pragma unroll
            for (int s = 0; s < 8; ++s) P[s] = __expf(lg_lds[(tb + s) * NL + j]);
#pragma unroll
            for (int s = 0; s < 8; ++s) {
                const int t = tb + s;
                const float r0 = rlane(A, 0), r1 = rlane(A, 1), r2 = rlane(A, 2),
                            r3 = rlane(A, 3), r4 = rlane(A, 4), r5 = rlane(A, 5),
                            r6 = rlane(A, 6), r7 = rlane(A, 7), r8 = rlane(A, 8);
                float p0 = r0 * E[0]; p0 = fmaf(r1, E[1], p0); p0 = fmaf(r2, E[2], p0);
                float p1 = r3 * E[3]; p1 = fmaf(r4, E[4], p1); p1 = fmaf(r5, E[5], p1);
                float p2 = r6 * E[6]; p2 = fmaf(r7, E[7], p2); p2 = fmaf(r8, E[8], p2);
                const float An = ((p0 + p1) + p2) * P[s];
                A = (t < sl) ? An : A;
            }
            // exact pow2 renorm: m is positive & normal here.
            const float m = fmaxf(fmaxf(
                fmaxf(fmaxf(rlane(A, 0), rlane(A, 1)), fmaxf(rlane(A, 2), rlane(A, 3))),
                fmaxf(fmaxf(rlane(A, 4), rlane(A, 5)), fmaxf(rlane(A, 6), rlane(A, 7)))),
                rlane(A, 8));
            const int ex = (int)((__float_as_uint(m) >> 23) & 0xFFu) - 126; // frexp exp
            const float sc = __uint_as_float((uint32_t)(127 - ex) << 23);   // 2^-ex
            A *= sc;
            lc += ex;
        }
        const float sum = ((rlane(A, 0) + rlane(A, 1)) + (rlane(A, 2) + rlane(A, 3))) +
                          ((rlane(A, 4) + rlane(A, 5)) + (rlane(A, 6) + rlane(A, 7))) +
                          rlane(A, 8);
        const float logZ = logf(sum) +
            ((float)lc + 3.0f * (float)(sl - 1)) * 0.6931471805599453f;
        if (lane == 0) stats[b * 8 + 1] = logZ;
    } else if (wv == 1) {
        // ---- viterbi value scan; alpha vectors to LDS, argmax deferred ----
        const int j = lane < NL ? lane : 0;
        float tc[NL];
#pragma unroll
        for (int i = 0; i < NL; ++i) tc[i] = trans_lds[i * NL + j];
        float v = lg_lds[j];
        if (lane < NL) val_lds[j] = v;
        for (int tb = 1; tb < BT + 8; tb += 8) {
            float lv[8];
#pragma unroll
            for (int s = 0; s < 8; ++s) lv[s] = lg_lds[(tb + s) * NL + j];
#pragma unroll
            for (int s = 0; s < 8; ++s) {
                const int t = tb + s;
                const float r0 = rlane(v, 0), r1 = rlane(v, 1), r2 = rlane(v, 2),
                            r3 = rlane(v, 3), r4 = rlane(v, 4), r5 = rlane(v, 5),
                            r6 = rlane(v, 6), r7 = rlane(v, 7), r8 = rlane(v, 8);
                const float c0 = r0 + tc[0], c1 = r1 + tc[1], c2 = r2 + tc[2],
                            c3 = r3 + tc[3], c4 = r4 + tc[4], c5 = r5 + tc[5],
                            c6 = r6 + tc[6], c7 = r7 + tc[7], c8 = r8 + tc[8];
                const float m = fmaxf(fmaxf(fmaxf(fmaxf(c0, c1), c2),
                                            fmaxf(fmaxf(c3, c4), c5)),
                                      fmaxf(fmaxf(c6, c7), c8));
                const float nv = m + lv[s];
                v = (t < sl) ? nv : v;
                if (lane < NL && t < BT) val_lds[t * NL + lane] = v;
            }
        }
        // last tag = first-argmax(alphaT)
        const float r0 = rlane(v, 0), r1 = rlane(v, 1), r2 = rlane(v, 2),
                    r3 = rlane(v, 3), r4 = rlane(v, 4), r5 = rlane(v, 5),
                    r6 = rlane(v, 6), r7 = rlane(v, 7), r8 = rlane(v, 8);
        const float m = fmaxf(fmaxf(fmaxf(fmaxf(r0, r1), r2),
                                    fmaxf(fmaxf(r3, r4), r5)),
                              fmaxf(fmaxf(r6, r7), r8));
        const int last = (r0 == m) ? 0 : (r1 == m) ? 1 : (r2 == m) ? 2 :
                         (r3 == m) ? 3 : (r4 == m) ? 4 : (r5 == m) ? 5 :
                         (r6 == m) ? 6 : (r7 == m) ? 7 : 8;
        if (lane == 0) vit_lds[BT - 1] = (uint8_t)last;
    } else if (wv == 2) {
        // ---- gold-path score ----
        float s = 0.f;
        for (int t = lane; t < BT; t += 64) {
            const int lb = lab[t];
            if (t < sl) {
                s += lg_lds[t * NL + lb];
                if (t >= 1) s += trans_lds[lab[t - 1] * NL + lb];
            }
        }
#pragma unroll
        for (int off = 32; off >= 1; off >>= 1) s += __shfl_xor(s, off, 64);
        if (lane == 0) stats[b * 8 + 0] = s;
    }
    __syncthreads();

    // ---- recompute backpointers in parallel (bit-exact first-max) ----
    for (int idx = tid; idx < (BT - 1) * NL; idx += 256) {
        const int tm1 = idx / NL;
        const int jj  = idx - tm1 * NL;
        const int t   = tm1 + 1;
        int bi;
        if (t >= sl) bi = jj;
        else {
            float best = val_lds[tm1 * NL] + trans_lds[jj];
            bi = 0;
#pragma unroll
            for (int i = 1; i < NL; ++i) {
                const float c = val_lds[tm1 * NL + i] + trans_lds[i * NL + jj];
                if (c > best) { best = c; bi = i; }
            }
        }
        bp_lds[idx] = (uint8_t)bi;
    }
    __syncthreads();

    // ---- pack bp rows: 9 x 4 bits -> u64 ----
    for (int r = tid; r < BT - 1; r += 256) {
        uint64_t p = 0;
#pragma unroll
        for (int i = 0; i < NL; ++i)
            p |= (uint64_t)bp_lds[r * NL + i] << (4 * i);
        packed_lds[r] = p;
    }
    __syncthreads();

    // ---- serial backtrack (address-independent LDS reads + 2-op extract) ----
    if (tid == 0) {
        int tag = vit_lds[BT - 1];
        for (int t = BT - 2; t >= 0; --t) {
            const uint64_t row = packed_lds[t];
            tag = (int)((row >> (4 * tag)) & 15u);
            vit_lds[t] = (uint8_t)tag;
        }
    }
    __syncthreads();

    // ---- stats + vit output ----
    float accv = 0.f, tpv = 0.f, tnv = 0.f, fpv = 0.f;
    for (int t = tid; t < BT; t += 256) {
        const int tg = vit_lds[t];
        const int lb = lab[t];
        const bool msk = t < sl;
        vit_out[(size_t)b * BT + t] = (float)tg;
        if (msk && tg == lb) accv += 1.f;
        if (lb > 0 && tg == lb) tpv += 1.f;
        if (lb > 0 && tg != lb) tnv += 1.f;
        if (msk && lb == 0 && tg > 0) fpv += 1.f;
    }
#pragma unroll
    for (int off = 32; off >= 1; off >>= 1) {
        accv += __shfl_xor(accv, off, 64);
        tpv  += __shfl_xor(tpv,  off, 64);
        tnv  += __shfl_xor(tnv,  off, 64);
        fpv  += __shfl_xor(fpv,  off, 64);
    }
    if (lane == 0) { xw[0][wv] = accv; xw[1][wv] = tpv; xw[2][wv] = tnv; xw[3][wv] = fpv; }
    __syncthreads();
    if (tid == 0) {
        stats[b * 8 + 2] = xw[0][0] + xw[0][1] + xw[0][2] + xw[0][3];
        stats[b * 8 + 3] = xw[1][0] + xw[1][1] + xw[1][2] + xw[1][3];
        stats[b * 8 + 4] = xw[2][0] + xw[2][1] + xw[2][2] + xw[2][3];
        stats[b * 8 + 5] = xw[3][0] + xw[3][1] + xw[3][2] + xw[3][3];
    }
}

// ---------------------------------------------------------------------------
// Kernel 3: reduce the 64 per-batch partials -> tp, tn, fp, loss, accuracy
// ---------------------------------------------------------------------------
__global__ __launch_bounds__(64) void finalize_kernel(
    const float* __restrict__ stats, const int* __restrict__ seqlen,
    float* __restrict__ out)
{
    const int lane = threadIdx.x;  // one lane per batch
    float score = stats[lane * 8 + 0];
    float logZ  = stats[lane * 8 + 1];
    float accv  = stats[lane * 8 + 2];
    float tpv   = stats[lane * 8 + 3];
    float tnv   = stats[lane * 8 + 4];
    float fpv   = stats[lane * 8 + 5];
    float nll   = logZ - score;
    float slf   = (float)seqlen[lane];
#pragma unroll
    for (int off = 32; off >= 1; off >>= 1) {
        nll  += __shfl_xor(nll,  off, 64);
        accv += __shfl_xor(accv, off, 64);
        tpv  += __shfl_xor(tpv,  off, 64);
        tnv  += __shfl_xor(tnv,  off, 64);
        fpv  += __shfl_xor(fpv,  off, 64);
        slf  += __shfl_xor(slf,  off, 64);
    }
    if (lane == 0) {
        out[NB * BT + 0] = tpv;
        out[NB * BT + 1] = tnv;
        out[NB * BT + 2] = fpv;
        out[NB * BT + 3] = nll / (float)NB;
        out[NB * BT + 4] = accv / slf;
    }
}

extern "C" void kernel_launch(void* const* d_in, const int* in_sizes, int n_in,
                              void* d_out, int out_size, void* d_ws, size_t ws_size,
                              hipStream_t stream)
{
    const float* x      = (const float*)d_in[0];
    const float* W      = (const float*)d_in[1];
    const float* bias   = (const float*)d_in[2];
    const float* trans  = (const float*)d_in[3];
    const int*   label  = (const int*)d_in[4];
    const int*   seqlen = (const int*)d_in[5];
    // d_in[6] = mask: recomputed from seqlen, unused

    float* out    = (float*)d_out;
    float* logits = (float*)d_ws;                  // 64*512*9 floats
    float* stats  = logits + (size_t)NB * BT * NL; // 64*8 floats

    gemm_kernel<<<512, 256, 0, stream>>>(x, W, bias, logits);
    crf_kernel<<<NB, 256, 0, stream>>>(logits, trans, label, seqlen, out, stats);
    finalize_kernel<<<1, 64, 0, stream>>>(stats, seqlen, out);
}